// Round 7
// baseline (329.761 us; speedup 1.0000x reference)
//
#include <hip/hip_runtime.h>

#define HW    256
#define HW2   65536      // HW*HW
#define BS    128
#define NTS   1024       // scatter threads/block
#define QPB   16384      // float4 quads per image plane (HW2/4)
#define HQ    8192       // quads per half plane

// ============================ NEW 2-KERNEL PATH ============================
// ws layout: W16[2][BS][HW2] u16 (32 MB) | packed[BS][128*128] float4 (32 MB)
// Winner semantics: W[gy,gx] = max l (l=h*256+w) == reference scatter's
// last-in-row-major-order-wins; "no writer" (0) is output-equivalent to
// winner l=0 (both sample (0,0), valid). Proven absmax 0.0 (rounds 1,3,4,6).
// Input-half split: winner = max(maxHalf0, maxHalf1), merged in gather.

// Packed-u16 max into LDS via 32-bit CAS (round-1 proven).
__device__ __forceinline__ void lds_max_u16(unsigned int* W32, int cell, unsigned int val) {
    unsigned int* word = W32 + (cell >> 1);
    unsigned int sh = (cell & 1) << 4;
    unsigned int assumed = *word;
    while (((assumed >> sh) & 0xFFFFu) < val) {
        unsigned int nw = (assumed & ~(0xFFFFu << sh)) | (val << sh);
        unsigned int prev = atomicCAS(word, assumed, nw);
        if (prev == assumed) break;
        assumed = prev;
    }
}

// Block = (batch, input-half). Reads own half of grid (no dup), full seg
// (flag only), scatters into full-plane LDS u16 winner, packs even-even
// (depth*m, conf, m) float4, writes partial winner array out.
__global__ __launch_bounds__(NTS, 1) void scatter_kernel(
        const float* __restrict__ grid,
        const float* __restrict__ seg,
        const float* __restrict__ conf,
        const float* __restrict__ depth,
        unsigned short* __restrict__ W16,
        float4* __restrict__ packed) {
    __shared__ unsigned short Wl[HW2];   // 128 KB
    __shared__ int red[16];
    __shared__ int flag_s;

    const int b    = blockIdx.x & (BS - 1);
    const int h    = blockIdx.x >> 7;          // input half (b and b+128 same XCD)
    const int tid  = threadIdx.x;
    const int wave = tid >> 6;
    const int lane = tid & 63;
    unsigned int* W32 = (unsigned int*)Wl;

    const float* segb   = seg   + (size_t)b * HW2;
    const float* confb  = conf  + (size_t)b * HW2;
    const float* depthb = depth + (size_t)b * HW2;

    // ---- zero winner; read seg (own half -> mbits, other half -> count) ---
    {
        uint4* Wz = (uint4*)W32;                 // 8192 uint4
        #pragma unroll
        for (int k = 0; k < 8; ++k) Wz[tid + k * NTS] = make_uint4(0u, 0u, 0u, 0u);
    }
    unsigned int mbits = 0u;
    int cnt = 0;
    {
        const float4* s4 = (const float4*)segb;
        #pragma unroll
        for (int k = 0; k < 8; ++k) {
            float4 v = s4[h * HQ + tid + k * NTS];
            unsigned q = (v.x > 0.5f ? 1u : 0u) | (v.y > 0.5f ? 2u : 0u) |
                         (v.z > 0.5f ? 4u : 0u) | (v.w > 0.5f ? 8u : 0u);
            mbits |= q << (k * 4);
            cnt += __popc(q);
        }
        #pragma unroll
        for (int k = 0; k < 8; ++k) {
            float4 v = s4[(1 - h) * HQ + tid + k * NTS];
            cnt += (v.x > 0.5f) + (v.y > 0.5f) + (v.z > 0.5f) + (v.w > 0.5f);
        }
    }
    for (int off = 32; off > 0; off >>= 1) cnt += __shfl_down(cnt, off);
    if (lane == 0) red[wave] = cnt;
    __syncthreads();
    if (tid == 0) {
        int t = 0;
        #pragma unroll
        for (int w = 0; w < 16; ++w) t += red[w];
        flag_s = (t == 0) ? 1 : 0;
    }
    __syncthreads();
    const int flagb = flag_s;

    // ---- scatter own half's pixels into full-plane LDS winner ------------
    {
        const float4* gx4 = (const float4*)(grid + (size_t)(2 * b) * HW2);
        const float4* gy4 = (const float4*)(grid + (size_t)(2 * b + 1) * HW2);
        int masked_max = -1;  // masked pixels (gridm==0) all target cell (128,128)
        #pragma unroll 4
        for (int k = 0; k < 8; ++k) {
            int i = h * HQ + tid + k * NTS;      // global quad in plane
            float4 X = gx4[i];
            float4 Y = gy4[i];
            int hw0 = i * 4;
            float xa[4] = {X.x, X.y, X.z, X.w};
            float ya[4] = {Y.x, Y.y, Y.z, Y.w};
            #pragma unroll
            for (int j = 0; j < 4; ++j) {
                bool m = flagb || ((mbits >> (k * 4 + j)) & 1u);
                if (m) {
                    float fx = (xa[j] + 1.0f) * 0.5f * 256.0f;  // trunc==floor (>=0)
                    float fy = (ya[j] + 1.0f) * 0.5f * 256.0f;
                    int gxi = min(max((int)fx, 0), HW - 1);
                    int gyi = min(max((int)fy, 0), HW - 1);
                    lds_max_u16(W32, gyi * HW + gxi, (unsigned int)(hw0 + j));
                } else {
                    masked_max = hw0 + j;        // k increases -> last is max
                }
            }
        }
        int mm = masked_max;
        for (int off = 32; off > 0; off >>= 1) mm = max(mm, __shfl_xor(mm, off));
        if (lane == 0 && mm >= 0)
            lds_max_u16(W32, 128 * HW + 128, (unsigned int)mm);
    }

    // ---- pack even-even cells of own half: (depth*m, conf, m, 0) ---------
    {
        float4* packb = packed + (size_t)b * 16384;
        #pragma unroll
        for (int rr = 0; rr < 4; ++rr) {
            int rl = wave * 4 + rr;              // 0..63
            int r  = 128 * h + 2 * rl;           // even global row in own half
            int qr = r * 64 + lane;              // f4 quad index
            float4 d = ((const float4*)depthb)[qr];
            float4 c = ((const float4*)confb)[qr];
            float4 s = ((const float4*)segb)[qr];
            float m0 = (flagb || s.x > 0.5f) ? 1.0f : 0.0f;
            float m1 = (flagb || s.z > 0.5f) ? 1.0f : 0.0f;
            int p = (r >> 1) * 128 + 2 * lane;
            packb[p]     = make_float4(d.x * m0, c.x, m0, 0.0f);
            packb[p + 1] = make_float4(d.z * m1, c.z, m1, 0.0f);
        }
    }
    __syncthreads();

    // ---- write partial winner array (full plane, coalesced) --------------
    {
        unsigned short* Wout = W16 + ((size_t)h * BS + b) * HW2;
        const uint4* Wl4 = (const uint4*)Wl;     // 8192 uint4
        #pragma unroll
        for (int k = 0; k < 8; ++k)
            ((uint4*)Wout)[tid + k * NTS] = Wl4[tid + k * NTS];
    }
}

// 2048 blocks x 256. Block->batch mapping keeps batch b on XCD b&7 (same as
// scatter wrote W16/packed) so those reads L2-hit. One random float4 load per
// pixel into a 256KB/batch footprint; ix/280 via 128-entry LDS LUT.
__global__ __launch_bounds__(256, 8) void gather_kernel(
        const unsigned short* __restrict__ W16,
        const float4* __restrict__ packed,
        float* __restrict__ out) {
    __shared__ float lut[128];
    if (threadIdx.x < 128) lut[threadIdx.x] = (float)(2 * threadIdx.x) / 280.0f;
    __syncthreads();

    const int B   = blockIdx.x;
    const int xcd = B & 7;
    const int k   = B >> 3;
    const int b   = (k & 15) * 8 + xcd;          // [0,128), all slices same XCD
    const int s   = k >> 4;                      // slice 0..15
    const int q0  = s * 1024;

    const unsigned short* W0 = W16 + (size_t)b * HW2;
    const unsigned short* W1 = W16 + ((size_t)BS + b) * HW2;
    const float4* packb = packed + (size_t)b * 16384;
    float4* out4 = (float4*)out;
    const size_t dkBase = (size_t)(b * 3) * QPB;
    const size_t O1 = (size_t)BS * 3 * QPB + (size_t)b * QPB;
    const size_t O2 = (size_t)BS * 4 * QPB + (size_t)b * QPB;

    #pragma unroll
    for (int t = 0; t < 4; ++t) {
        int q = q0 + threadIdx.x + t * 256;      // quad of 4 cells
        uint2 a  = ((const uint2*)W0)[q];
        uint2 c2 = ((const uint2*)W1)[q];
        unsigned la[4] = { max(a.x & 0xFFFFu, c2.x & 0xFFFFu),
                           max(a.x >> 16,     c2.x >> 16),
                           max(a.y & 0xFFFFu, c2.y & 0xFFFFu),
                           max(a.y >> 16,     c2.y >> 16) };
        float o0[4], o1[4], o2v[4], oc[4], om[4];
        #pragma unroll
        for (int j = 0; j < 4; ++j) {
            unsigned l = la[j];
            int ix = (int)(l & 255u) & ~1;       // even-snap (round-half-even)
            int iy = (int)(l >> 8) & ~1;
            float4 p = packb[(iy >> 1) * 128 + (ix >> 1)];
            float m = p.z;
            o0[j]  = lut[ix >> 1] * m;           // == (ix/280.0f)*m bit-exact
            o1[j]  = lut[iy >> 1] * m;
            o2v[j] = p.x;                        // depth*m (pre-masked)
            oc[j]  = p.y;
            om[j]  = m;
        }
        out4[dkBase + q]           = make_float4(o0[0], o0[1], o0[2], o0[3]);
        out4[dkBase + QPB + q]     = make_float4(o1[0], o1[1], o1[2], o1[3]);
        out4[dkBase + 2 * QPB + q] = make_float4(o2v[0], o2v[1], o2v[2], o2v[3]);
        out4[O1 + q]               = make_float4(oc[0], oc[1], oc[2], oc[3]);
        out4[O2 + q]               = make_float4(om[0], om[1], om[2], om[3]);
    }
}

// ======================= FALLBACK (round-6 fused, measured) ================
#define NT 1024
#define QQ 4096
__global__ __launch_bounds__(NT, 8) void fused_kernel(
        const float* __restrict__ grid,
        const float* __restrict__ seg,
        const float* __restrict__ conf,
        const float* __restrict__ depth,
        float* __restrict__ out) {
    __shared__ unsigned int Wl[HW2 / 4];
    __shared__ unsigned long long segbits[4][256];
    __shared__ int red[16];
    __shared__ int flag_s;
    const int b       = blockIdx.x & (BS - 1);
    const int quarter = blockIdx.x >> 7;
    const int tid  = threadIdx.x;
    const int wave = tid >> 6;
    const int lane = tid & 63;
    const float* segb   = seg   + (size_t)b * HW2;
    const float* confb  = conf  + (size_t)b * HW2;
    const float* depthb = depth + (size_t)b * HW2;
    {
        uint4* Wz = (uint4*)Wl;
        #pragma unroll
        for (int k = 0; k < 4; ++k) Wz[tid + k * NT] = make_uint4(0u, 0u, 0u, 0u);
    }
    unsigned long long mbits = 0ULL;
    int cnt = 0;
    {
        const float4* s4 = (const float4*)segb;
        #pragma unroll
        for (int k = 0; k < 16; ++k) {
            int i = tid + k * NT;
            float4 v = s4[i];
            bool px = v.x > 0.5f, py = v.y > 0.5f, pz = v.z > 0.5f, pw = v.w > 0.5f;
            unsigned long long bx = __ballot(px), by = __ballot(py);
            unsigned long long bz = __ballot(pz), bw = __ballot(pw);
            if (lane == 0) {
                int wi = wave + k * 16;
                segbits[0][wi] = bx; segbits[1][wi] = by;
                segbits[2][wi] = bz; segbits[3][wi] = bw;
                cnt += __popcll(bx) + __popcll(by) + __popcll(bz) + __popcll(bw);
            }
            unsigned long long q = (px ? 1ULL : 0ULL) | (py ? 2ULL : 0ULL) |
                                   (pz ? 4ULL : 0ULL) | (pw ? 8ULL : 0ULL);
            mbits |= q << (k * 4);
        }
    }
    if (lane == 0) red[wave] = cnt;
    __syncthreads();
    if (tid == 0) {
        int t = 0;
        #pragma unroll
        for (int w = 0; w < 16; ++w) t += red[w];
        flag_s = (t == 0) ? 1 : 0;
    }
    __syncthreads();
    const int flagb = flag_s;
    {
        const float4* gx4 = (const float4*)(grid + (size_t)(2 * b) * HW2);
        const float4* gy4 = (const float4*)(grid + (size_t)(2 * b + 1) * HW2);
        int masked_max = -1;
        #pragma unroll 4
        for (int k = 0; k < 16; ++k) {
            int i = tid + k * NT;
            float4 X = gx4[i];
            float4 Y = gy4[i];
            int hw0 = i * 4;
            float xa[4] = {X.x, X.y, X.z, X.w};
            float ya[4] = {Y.x, Y.y, Y.z, Y.w};
            #pragma unroll
            for (int j = 0; j < 4; ++j) {
                bool m = flagb || ((mbits >> (k * 4 + j)) & 1ULL);
                if (m) {
                    float fx = (xa[j] + 1.0f) * 0.5f * 256.0f;
                    float fy = (ya[j] + 1.0f) * 0.5f * 256.0f;
                    int gxi = min(max((int)fx, 0), HW - 1);
                    int gyi = min(max((int)fy, 0), HW - 1);
                    if ((gyi >> 6) == quarter)
                        atomicMax(&Wl[(gyi & 63) * HW + gxi], (unsigned int)(hw0 + j));
                } else {
                    masked_max = hw0 + j;
                }
            }
        }
        int mm = masked_max;
        for (int off = 32; off > 0; off >>= 1) mm = max(mm, __shfl_xor(mm, off));
        if (quarter == 2 && lane == 0 && mm >= 0)
            atomicMax(&Wl[(128 & 63) * HW + 128], (unsigned int)mm);
    }
    __syncthreads();
    float4* out4 = (float4*)out;
    const size_t dkBase = (size_t)(b * 3) * QPB;
    const size_t O1q = (size_t)BS * 3 * QPB + (size_t)b * QPB;
    const size_t O2q = (size_t)BS * 4 * QPB + (size_t)b * QPB;
    #pragma unroll 4
    for (int k = 0; k < 4; ++k) {
        int i = tid + k * NT;
        uint4 wv = ((const uint4*)Wl)[i];
        unsigned la[4] = {wv.x, wv.y, wv.z, wv.w};
        float o0[4], o1[4], o2[4], oc[4], om[4];
        #pragma unroll
        for (int j = 0; j < 4; ++j) {
            unsigned l = la[j];
            int ix = (int)(l & 255u) & ~1;
            int iy = (int)(l >> 8) & ~1;
            int off = iy * HW + ix;
            int q = off >> 2;
            float m;
            if (flagb) m = 1.0f;
            else       m = (float)((segbits[off & 3][q >> 6] >> (q & 63)) & 1ULL);
            o0[j] = ((float)ix / 280.0f) * m;
            o1[j] = ((float)iy / 280.0f) * m;
            o2[j] = depthb[off] * m;
            oc[j] = confb[off];
            om[j] = m;
        }
        size_t gq = (size_t)quarter * QQ + i;
        out4[dkBase + gq]           = make_float4(o0[0], o0[1], o0[2], o0[3]);
        out4[dkBase + QPB + gq]     = make_float4(o1[0], o1[1], o1[2], o1[3]);
        out4[dkBase + 2 * QPB + gq] = make_float4(o2[0], o2[1], o2[2], o2[3]);
        out4[O1q + gq]              = make_float4(oc[0], oc[1], oc[2], oc[3]);
        out4[O2q + gq]              = make_float4(om[0], om[1], om[2], om[3]);
    }
}

extern "C" void kernel_launch(void* const* d_in, const int* in_sizes, int n_in,
                              void* d_out, int out_size, void* d_ws, size_t ws_size,
                              hipStream_t stream) {
    const float* grid  = (const float*)d_in[0];
    const float* seg   = (const float*)d_in[1];
    const float* conf  = (const float*)d_in[2];
    const float* depth = (const float*)d_in[3];
    float* out = (float*)d_out;

    const size_t W16Bytes  = (size_t)2 * BS * HW2 * sizeof(unsigned short); // 32 MB
    const size_t packBytes = (size_t)BS * 16384 * sizeof(float4);           // 32 MB
    if (ws_size >= W16Bytes + packBytes) {
        unsigned short* W16 = (unsigned short*)d_ws;
        float4* packed = (float4*)((char*)d_ws + W16Bytes);
        scatter_kernel<<<BS * 2, NTS, 0, stream>>>(grid, seg, conf, depth, W16, packed);
        gather_kernel<<<2048, 256, 0, stream>>>(W16, packed, out);
    } else {
        fused_kernel<<<BS * 4, NT, 0, stream>>>(grid, seg, conf, depth, out);
    }
}